// Round 10
// baseline (88.750 us; speedup 1.0000x reference)
//
#include <hip/hip_runtime.h>

constexpr int V  = 50257;   // vocab
constexpr int D  = 300;     // vocab dim
constexpr int KD = 512;     // decoder dim
constexpr int B  = 16;      // batch

constexpr int ROWS = 64;                      // rows per k_att_pv block
constexpr int NBLK = (V + ROWS - 1) / ROWS;   // 786 blocks
constexpr int NSUB = NBLK * 2;                // 1572 32-row subtiles

constexpr float NEG_HUGE = -1.0e30f;

// ws layout (float offsets)
constexpr size_t WS_QT    = 0;                 // 5120 swizzled q
constexpr size_t WS_STAT  = 5120;              // NSUB*16*2 = 50304
constexpr size_t WS_SCALE = 55424;             // 16*NSUB   = 25152
constexpr size_t WS_WPART = 80576;             // NBLK*4800 = 3772800 (~15 MB)

typedef float v2f __attribute__((ext_vector_type(2)));

struct f4 { float v[4]; };
__device__ __forceinline__ f4 ld4(const float* p) {
    float4 t = *(const float4*)p;
    return {t.x, t.y, t.z, t.w};
}

#define AS1 __attribute__((address_space(1)))
#define AS3 __attribute__((address_space(3)))
#define DPPF(x, CTRL) __int_as_float(__builtin_amdgcn_mov_dpp(__float_as_int(x), (CTRL), 0xF, 0xF, false))

// ---------------------------------------------------------------------------
// K1: q = dh @ Wdec^T + bdec, written PRE-SWIZZLED (+ zero pad to d=320).
__global__ void __launch_bounds__(256) k_query(
    const float* __restrict__ dh, const float* __restrict__ Wdec,
    const float* __restrict__ bdec, float* __restrict__ q_swz)
{
    int wid  = (blockIdx.x * 256 + threadIdx.x) >> 6;
    int lane = threadIdx.x & 63;
    if (wid >= 320 * 16) return;
    int d = wid >> 4, b = wid & 15;
    float s = 0.f;
    if (d < D) {
        const float* wrow = Wdec + (size_t)d * KD;
        const float* hrow = dh + (size_t)b * KD;
        for (int k = lane; k < KD; k += 64) s += wrow[k] * hrow[k];
        #pragma unroll
        for (int off = 32; off; off >>= 1) s += __shfl_down(s, off, 64);
        s += bdec[d];
    }
    if (lane == 0) {
        int P = (d >> 1) * 8 + ((((d & 1) << 2) | (b >> 2)) ^ ((d >> 2) & 7));
        q_swz[P * 4 + (b & 3)] = (d < D) ? s : 0.f;
    }
}

// ---------------------------------------------------------------------------
// K2: fused att + softmax-stats + PV. Per block: 64 rows as 2 subtiles of 32
// through ONE 38.4 KB LDS buffer. Per subtile: MAC (r9 loop) -> satt ->
// running-max stats (m_ref, s_sub -> blkstats) -> p = exp(att - m_ref)
// overlaid in LDS + stored to global alpha region -> PV accumulate
// (rescaled by exp(M_old - M_new)). End: Wpart[blk][16][300].
__global__ void __launch_bounds__(256, 2) k_att_pv(
    const float* __restrict__ E, const float* __restrict__ q_swz,
    const float* __restrict__ wf, const float* __restrict__ bf,
    float* __restrict__ alpha, float* __restrict__ blkstats,
    float* __restrict__ wpart)
{
    __shared__ __align__(16) float sq[5120];    // swizzled q
    __shared__ __align__(16) float seE[9600];   // 32 rows x 300
    __shared__ float satt[512];                 // [lrow 32][b 16]: att, then p
    __shared__ float sm[16], sf[16], sold[16];

    const int t    = threadIdx.x;
    const int slot = t & 15;
    const int rg   = t >> 4;         // 0..15
    const int v0   = blockIdx.x * ROWS;

    // DMA q (5 x 4KB, linear)
    #pragma unroll
    for (int k = 0; k < 5; ++k)
        __builtin_amdgcn_global_load_lds((const AS1 void*)(q_swz + k * 1024 + t * 4),
                                         (AS3 void*)(sq + k * 1024 + t * 4), 16, 0, 0);
    // DMA E subtile 0 (contiguous rows)
    {
        int nr = V - v0; if (nr > 32) nr = 32;
        int nflt = nr * 300;
        const float* Eb = E + (size_t)v0 * 300;
        #pragma unroll
        for (int k = 0; k < 10; ++k) {
            int o = k * 1024 + t * 4;
            if (o < nflt)
                __builtin_amdgcn_global_load_lds((const AS1 void*)(Eb + o),
                                                 (AS3 void*)(seE + o), 16, 0, 0);
        }
        for (int o = t * 4; o < 9600; o += 1024)
            if (o >= nflt) *(float4*)(seE + o) = make_float4(0.f, 0.f, 0.f, 0.f);
    }

    // w into registers
    f4 wreg[5];
    #pragma unroll
    for (int k = 0; k < 4; ++k) wreg[k] = ld4(wf + k * 64 + slot * 4);
    if (slot < 11) wreg[4] = ld4(wf + 256 + slot * 4);
    else { wreg[4].v[0] = wreg[4].v[1] = wreg[4].v[2] = wreg[4].v[3] = 0.f; }
    #pragma unroll
    for (int i = 0; i < 4; ++i)
        if (256 + slot * 4 + i >= D && slot < 11) wreg[4].v[i] = 0.f;
    const float bfull = bf[0];

    // per-thread sq read offsets (r8/r9-verified swizzle)
    int xq[2][4];
    #pragma unroll
    for (int i1 = 0; i1 < 2; ++i1)
        #pragma unroll
        for (int bq = 0; bq < 4; ++bq)
            xq[i1][bq] = slot * 64 + 4 * (((i1 << 2) | bq) ^ (slot & 7));

    if (t < 16) sold[t] = NEG_HUGE;

    // PV thread mapping + accumulators (live across subtiles)
    const int dgrp = t & 15;
    const int rh   = (t >> 4) & 1;
    const int bp   = t >> 5;          // 0..7
    const int b0   = bp * 2, b1 = bp * 2 + 1;
    f4 pvA[5], pvB[5];
    #pragma unroll
    for (int k = 0; k < 5; ++k)
        #pragma unroll
        for (int c4 = 0; c4 < 4; ++c4) { pvA[k].v[c4] = 0.f; pvB[k].v[c4] = 0.f; }

    asm volatile("s_waitcnt vmcnt(0)" ::: "memory");
    __syncthreads();   // q + E(sub0) + pad + sold ready

    const int c    = slot & 3;
    const int jown = (slot >> 2) & 1;
    const int dup  = slot >> 3;
    const int lrow = rg + 16 * jown;

    for (int sub = 0; sub < 2; ++sub) {
        const int vs = v0 + sub * 32;

        // ---- MAC over 5 d-tiles (r9-verified) ----
        v2f acc2[2][8];
        #pragma unroll
        for (int j = 0; j < 2; ++j)
            #pragma unroll
            for (int p = 0; p < 8; ++p) acc2[j][p] = (v2f){0.f, 0.f};

        #pragma unroll
        for (int tt = 0; tt < 5; ++tt) {
            f4 e0 = ld4(seE + rg * 300 + tt * 64 + slot * 4);
            f4 e1 = ld4(seE + (rg + 16) * 300 + tt * 64 + slot * 4);
            const float* sqt = sq + tt * 1024;
            #pragma unroll
            for (int i = 0; i < 4; ++i) {
                float wi = wreg[tt].v[i];
                v2f w2 = {wi, wi};
                #pragma unroll
                for (int bq = 0; bq < 4; ++bq) {
                    f4 qv = ld4(sqt + (i >> 1) * 32 + xq[i & 1][bq]);
                    v2f qlo = {qv.v[0], qv.v[1]};
                    v2f qhi = {qv.v[2], qv.v[3]};
                    v2f z2  = {0.f, 0.f};
                    v2f ea  = {e0.v[i], e0.v[i]};
                    v2f lo0 = __builtin_elementwise_max(ea + qlo, z2);
                    v2f hi0 = __builtin_elementwise_max(ea + qhi, z2);
                    acc2[0][bq*2]   = __builtin_elementwise_fma(lo0, w2, acc2[0][bq*2]);
                    acc2[0][bq*2+1] = __builtin_elementwise_fma(hi0, w2, acc2[0][bq*2+1]);
                    v2f eb  = {e1.v[i], e1.v[i]};
                    v2f lo1 = __builtin_elementwise_max(eb + qlo, z2);
                    v2f hi1 = __builtin_elementwise_max(eb + qhi, z2);
                    acc2[1][bq*2]   = __builtin_elementwise_fma(lo1, w2, acc2[1][bq*2]);
                    acc2[1][bq*2+1] = __builtin_elementwise_fma(hi1, w2, acc2[1][bq*2+1]);
                }
            }
        }

        float acc[2][16];
        #pragma unroll
        for (int j = 0; j < 2; ++j)
            #pragma unroll
            for (int bq = 0; bq < 4; ++bq) {
                acc[j][bq*4+0] = acc2[j][bq*2][0];
                acc[j][bq*4+1] = acc2[j][bq*2][1];
                acc[j][bq*4+2] = acc2[j][bq*2+1][0];
                acc[j][bq*4+3] = acc2[j][bq*2+1][1];
            }

        // slot-reduce: DPP xor1/xor2, compact, shfl xor4/xor8
        #pragma unroll
        for (int j = 0; j < 2; ++j)
            #pragma unroll
            for (int b = 0; b < 16; ++b) {
                float x = acc[j][b];
                x += DPPF(x, 0xB1);
                x += DPPF(x, 0x4E);
                acc[j][b] = x;
            }
        float kept[2][4];
        #pragma unroll
        for (int j = 0; j < 2; ++j)
            #pragma unroll
            for (int kk = 0; kk < 4; ++kk) {
                float x = (c == 0) ? acc[j][kk]
                        : (c == 1) ? acc[j][4 + kk]
                        : (c == 2) ? acc[j][8 + kk]
                        :            acc[j][12 + kk];
                x += __shfl_xor(x, 4, 64);
                x += __shfl_xor(x, 8, 64);
                kept[j][kk] = x;
            }

        // owners write raw att (+bfull) into satt, NEG_HUGE for pad rows
        const int grow = vs + lrow;
        const bool ok  = grow < V;
        #pragma unroll
        for (int kk2 = 0; kk2 < 2; ++kk2) {
            int b = 4 * c + (dup ? 2 : 0) + kk2;
            float x0 = jown ? kept[1][kk2]     : kept[0][kk2];
            float x1 = jown ? kept[1][2 + kk2] : kept[0][2 + kk2];
            float x  = (dup ? x1 : x0) + bfull;
            satt[lrow * 16 + b] = ok ? x : NEG_HUGE;
        }
        __syncthreads();

        // per-b stats with running max
        if (t < 16) {
            float ms = NEG_HUGE;
            #pragma unroll 4
            for (int u = 0; u < 32; ++u) ms = fmaxf(ms, satt[u * 16 + t]);
            float Mn = fmaxf(sold[t], ms);
            float ss = 0.f;
            #pragma unroll 4
            for (int u = 0; u < 32; ++u) ss += __expf(satt[u * 16 + t] - Mn);
            size_t sg = ((size_t)blockIdx.x * 2 + sub) * 16 + t;
            blkstats[sg * 2]     = Mn;
            blkstats[sg * 2 + 1] = ss;
            sf[t] = __expf(sold[t] - Mn);
            sm[t] = Mn;
            sold[t] = Mn;
        }
        __syncthreads();

        // p overlay + global alpha store (p relative to current running max)
        #pragma unroll
        for (int kk2 = 0; kk2 < 2; ++kk2) {
            int b = 4 * c + (dup ? 2 : 0) + kk2;
            float p = __expf(satt[lrow * 16 + b] - sm[b]);
            satt[lrow * 16 + b] = p;
            if (ok) alpha[(size_t)b * V + grow] = p;
        }
        // rescale PV accumulators
        {
            float fA = sf[b0], fB = sf[b1];
            #pragma unroll
            for (int k = 0; k < 5; ++k)
                #pragma unroll
                for (int c4 = 0; c4 < 4; ++c4) {
                    pvA[k].v[c4] *= fA;
                    pvB[k].v[c4] *= fB;
                }
        }
        __syncthreads();   // p visible everywhere

        // PV: rows rh*16 .. rh*16+15, d quads dgrp*4 + 64k
        #pragma unroll 2
        for (int r = 0; r < 16; ++r) {
            int lr = rh * 16 + r;
            float pA = satt[lr * 16 + b0];
            float pB = satt[lr * 16 + b1];
            const float* er = seE + lr * 300 + dgrp * 4;
            #pragma unroll
            for (int k = 0; k < 5; ++k) {
                if (k < 4 || dgrp < 11) {
                    f4 e = ld4(er + k * 64);
                    #pragma unroll
                    for (int c4 = 0; c4 < 4; ++c4) {
                        pvA[k].v[c4] = fmaf(pA, e.v[c4], pvA[k].v[c4]);
                        pvB[k].v[c4] = fmaf(pB, e.v[c4], pvB[k].v[c4]);
                    }
                }
            }
        }
        __syncthreads();   // seE + satt reads complete

        // stage subtile 1 into the same buffer
        if (sub == 0) {
            int nr = V - (v0 + 32); if (nr > 32) nr = 32; if (nr < 0) nr = 0;
            int nflt = nr * 300;
            const float* Eb = E + (size_t)(v0 + 32) * 300;
            #pragma unroll
            for (int k = 0; k < 10; ++k) {
                int o = k * 1024 + t * 4;
                if (o < nflt)
                    __builtin_amdgcn_global_load_lds((const AS1 void*)(Eb + o),
                                                     (AS3 void*)(seE + o), 16, 0, 0);
            }
            for (int o = t * 4; o < 9600; o += 1024)
                if (o >= nflt) *(float4*)(seE + o) = make_float4(0.f, 0.f, 0.f, 0.f);
            asm volatile("s_waitcnt vmcnt(0)" ::: "memory");
            __syncthreads();
        }
    }

    // Wpart store: merge the two row-halves (lane xor 16), rh selects b of pair
    #pragma unroll
    for (int k = 0; k < 5; ++k)
        #pragma unroll
        for (int c4 = 0; c4 < 4; ++c4) {
            pvA[k].v[c4] += __shfl_xor(pvA[k].v[c4], 16, 64);
            pvB[k].v[c4] += __shfl_xor(pvB[k].v[c4], 16, 64);
        }
    {
        int bsel = rh ? b1 : b0;
        float* wp = wpart + (size_t)blockIdx.x * 4800 + bsel * 300;
        #pragma unroll
        for (int k = 0; k < 5; ++k) {
            int d = k * 64 + dgrp * 4;
            if (d < 300) {
                float4 s;
                if (rh) { s.x = pvB[k].v[0]; s.y = pvB[k].v[1]; s.z = pvB[k].v[2]; s.w = pvB[k].v[3]; }
                else    { s.x = pvA[k].v[0]; s.y = pvA[k].v[1]; s.z = pvA[k].v[2]; s.w = pvA[k].v[3]; }
                *(float4*)(wp + d) = s;
            }
        }
    }
}

// ---------------------------------------------------------------------------
// K3: combine subtile stats -> M_b, S_b; emit scale[b][sub] = exp(m-M)/S.
__global__ void __launch_bounds__(64) k_combine(
    const float* __restrict__ blkstats, float* __restrict__ scale)
{
    int b = blockIdx.x, lane = threadIdx.x;
    float m = NEG_HUGE;
    for (int cc = lane; cc < NSUB; cc += 64)
        m = fmaxf(m, blkstats[(size_t)(cc * 16 + b) * 2]);
    #pragma unroll
    for (int off = 32; off; off >>= 1) m = fmaxf(m, __shfl_xor(m, off, 64));
    float s = 0.f;
    for (int cc = lane; cc < NSUB; cc += 64)
        s += blkstats[(size_t)(cc * 16 + b) * 2 + 1] *
             __expf(blkstats[(size_t)(cc * 16 + b) * 2] - m);
    #pragma unroll
    for (int off = 32; off; off >>= 1) s += __shfl_xor(s, off, 64);
    float invS = 1.f / s;
    for (int cc = lane; cc < NSUB; cc += 64)
        scale[(size_t)b * NSUB + cc] =
            __expf(blkstats[(size_t)(cc * 16 + b) * 2] - m) * invS;
}

// ---------------------------------------------------------------------------
// K4: finish. Blocks [0,80): out[b][d] = sum_blk Wpart*scale[b][2blk+1].
//     Blocks [80,160): alpha *= scale[b][v>>5] in place.
__global__ void __launch_bounds__(512) k_finish(
    const float* __restrict__ wpart, const float* __restrict__ scale,
    float* __restrict__ alpha, float* __restrict__ out)
{
    __shared__ float red[512];
    int bi = blockIdx.x, t = threadIdx.x;
    if (bi < 80) {
        int b = bi / 5, dq = bi % 5;
        int dd = t & 63, blane = t >> 6;       // 8 w-chunks
        int d = dq * 64 + dd;
        float acc = 0.f;
        if (d < 300) {
            const float* sc = scale + (size_t)b * NSUB;
            int w0 = blane * 99, w1 = w0 + 99;
            if (w1 > NBLK) w1 = NBLK;
            int w = w0;
            for (; w + 8 <= w1; w += 8) {
                #pragma unroll
                for (int u = 0; u < 8; ++u)
                    acc = fmaf(wpart[(size_t)(w + u) * 4800 + b * 300 + d],
                               sc[2 * (w + u) + 1], acc);
            }
            for (; w < w1; ++w)
                acc = fmaf(wpart[(size_t)w * 4800 + b * 300 + d],
                           sc[2 * w + 1], acc);
        }
        red[blane * 64 + dd] = acc;
        __syncthreads();
        if (t < 64) {
            float s = 0.f;
            #pragma unroll
            for (int l = 0; l < 8; ++l) s += red[l * 64 + t];
            int d2 = dq * 64 + t;
            if (d2 < 300) out[b * 300 + d2] = s;
        }
    } else {
        int bid2 = bi - 80;
        int b = bid2 / 5, seg = bid2 % 5;
        const float* sc = scale + (size_t)b * NSUB;
        float* al = alpha + (size_t)b * V;
        #pragma unroll
        for (int i = 0; i < 5; ++i) {
            int v = seg * 10240 + i * 2048 + t * 4;
            if (v + 4 <= V) {
                float4 a = *(const float4*)(al + v);
                float s = sc[v >> 5];
                a.x *= s; a.y *= s; a.z *= s; a.w *= s;
                *(float4*)(al + v) = a;
            } else {
                for (int vv = v; vv < V && vv < v + 4; ++vv)
                    al[vv] *= sc[vv >> 5];
            }
        }
    }
}

// ---------------------------------------------------------------------------
extern "C" void kernel_launch(void* const* d_in, const int* in_sizes, int n_in,
                              void* d_out, int out_size, void* d_ws, size_t ws_size,
                              hipStream_t stream) {
    const float* dh   = (const float*)d_in[0];
    const float* E    = (const float*)d_in[1];
    const float* Wdec = (const float*)d_in[2];
    const float* bdec = (const float*)d_in[3];
    const float* wf   = (const float*)d_in[4];
    const float* bf   = (const float*)d_in[5];
    float* out = (float*)d_out;          // enc [0,4800), alpha [4800, ...)
    float* ws  = (float*)d_ws;

    float* q_swz = ws + WS_QT;
    float* stats = ws + WS_STAT;
    float* scale = ws + WS_SCALE;
    float* wpart = ws + WS_WPART;
    float* alpha = out + 4800;

    k_query<<<(320 * 16) / 4, 256, 0, stream>>>(dh, Wdec, bdec, q_swz);
    k_att_pv<<<NBLK, 256, 0, stream>>>(E, q_swz, wf, bf, alpha, stats, wpart);
    k_combine<<<B, 64, 0, stream>>>(stats, scale);
    k_finish<<<160, 512, 0, stream>>>(wpart, scale, alpha, out);
}

// Round 11
// 87.664 us; speedup vs baseline: 1.0124x; 1.0124x over previous
//
#include <hip/hip_runtime.h>

constexpr int V  = 50257;   // vocab
constexpr int D  = 300;     // vocab dim
constexpr int KD = 512;     // decoder dim
constexpr int B  = 16;      // batch

constexpr int ROWS = 64;                      // rows per k_att block
constexpr int NBLK = (V + ROWS - 1) / ROWS;   // 786 blocks
constexpr int NC  = 448;                      // wsum chunks
constexpr int RPC = 113;                      // rows per chunk, NC*RPC >= V

constexpr float NEG_HUGE = -1.0e30f;

// ws layout (float offsets)
constexpr size_t WS_QT   = 0;                              // 5120 (320 x 16)
constexpr size_t WS_STAT = 5120;                           // NBLK*32
constexpr size_t WS_MS   = WS_STAT + (size_t)NBLK * 32;    // 32
constexpr size_t WS_PART = WS_MS + 32;                     // NC*4800
constexpr size_t WS_TMP  = WS_PART + (size_t)NC * 4800;    // 16*4800

typedef float v2f __attribute__((ext_vector_type(2)));

struct f4 { float v[4]; };
__device__ __forceinline__ f4 ld4(const float* p) {
    float4 t = *(const float4*)p;
    return {t.x, t.y, t.z, t.w};
}

#define AS1 __attribute__((address_space(1)))
#define AS3 __attribute__((address_space(3)))

// ---------------------------------------------------------------------------
// K1: q_t[d*16+b] = dh@Wdec^T + bdec, plain [d][16] layout, zero-padded d<320.
__global__ void __launch_bounds__(256) k_query(
    const float* __restrict__ dh, const float* __restrict__ Wdec,
    const float* __restrict__ bdec, float* __restrict__ q_t)
{
    int wid  = (blockIdx.x * 256 + threadIdx.x) >> 6;
    int lane = threadIdx.x & 63;
    if (wid >= 320 * 16) return;
    int d = wid >> 4, b = wid & 15;
    float s = 0.f;
    if (d < D) {
        const float* wrow = Wdec + (size_t)d * KD;
        const float* hrow = dh + (size_t)b * KD;
        for (int k = lane; k < KD; k += 64) s += wrow[k] * hrow[k];
        #pragma unroll
        for (int off = 32; off; off >>= 1) s += __shfl_down(s, off, 64);
        s += bdec[d];
    }
    if (lane == 0) q_t[d * 16 + b] = (d < D) ? s : 0.f;
}

// ---------------------------------------------------------------------------
// K2: att[b,v] = sum_d relu(E[v,d]+q[b,d])*wf[d] + bf  (raw att stored).
// Thread (slot=t&15, bg=(t>>4)&3, wave=t>>6): q[20d x 4b] IN REGISTERS,
// wave streams one row at a time (4 rows/wave/subtile). E staged by DMA,
// 2 x 16-row buffers. Per row: 5 LDS b128 (multicast) vs ~320 VALU cyc.
// Per-row shfl_xor reduce over 16 slots; online (m,s) in regs; satt -> one
// coalesced att store per subtile; block (m,s) to blkstats.
__global__ void __launch_bounds__(256, 2) k_att(
    const float* __restrict__ E, const float* __restrict__ q_t,
    const float* __restrict__ wf, const float* __restrict__ bf,
    float* __restrict__ att, float* __restrict__ blkstats)
{
    __shared__ __align__(16) float seE[2][4832];  // 2 x (16 rows x 300 + pad)
    __shared__ float satt[256];                   // [r 16][b 16]
    __shared__ float sms[128];                    // wave stats

    const int t    = threadIdx.x;
    const int slot = t & 15;
    const int bg   = (t >> 4) & 3;
    const int wv   = t >> 6;
    const int v0   = blockIdx.x * ROWS;

    if (t < 32) { seE[0][4800 + t] = 0.f; seE[1][4800 + t] = 0.f; }

    // q -> registers: q2[(k*4+i)*2 + h] = v2f pair of batches bg*4.. (80 VGPR)
    v2f q2[40];
    #pragma unroll
    for (int k = 0; k < 5; ++k)
        #pragma unroll
        for (int i = 0; i < 4; ++i) {
            int d = k * 64 + slot * 4 + i;
            f4 qv = ld4(q_t + d * 16 + bg * 4);
            q2[(k * 4 + i) * 2]     = (v2f){qv.v[0], qv.v[1]};
            q2[(k * 4 + i) * 2 + 1] = (v2f){qv.v[2], qv.v[3]};
        }
    // w -> registers (zero beyond D)
    f4 wreg[5];
    #pragma unroll
    for (int k = 0; k < 4; ++k) wreg[k] = ld4(wf + k * 64 + slot * 4);
    if (slot < 11) wreg[4] = ld4(wf + 256 + slot * 4);
    else { wreg[4].v[0] = wreg[4].v[1] = wreg[4].v[2] = wreg[4].v[3] = 0.f; }
    const float bfull = bf[0];

    float m_r[4], s_r[4];
    #pragma unroll
    for (int j = 0; j < 4; ++j) { m_r[j] = NEG_HUGE; s_r[j] = 0.f; }

#define STAGE(S) do {                                                         \
    int nr = V - (v0 + (S) * 16); if (nr > 16) nr = 16;                       \
    int nflt = nr * 300;                                                      \
    const float* src = E + (size_t)(v0 + (S) * 16) * 300;                     \
    float* dst = &seE[(S) & 1][0];                                            \
    _Pragma("unroll")                                                         \
    for (int kk = 0; kk < 5; ++kk) {                                          \
        int o = kk * 1024 + t * 4;                                            \
        if (o < nflt)                                                         \
            __builtin_amdgcn_global_load_lds((const AS1 void*)(src + o),      \
                                             (AS3 void*)(dst + o), 16, 0, 0); \
    }                                                                         \
} while (0)

#define MACK(EV, K) do {                                                      \
    _Pragma("unroll")                                                         \
    for (int i = 0; i < 4; ++i) {                                             \
        v2f eb  = {EV.v[i], EV.v[i]};                                         \
        v2f wv2 = {wreg[K].v[i], wreg[K].v[i]};                               \
        a0 = __builtin_elementwise_fma(                                       \
            __builtin_elementwise_max(eb + q2[(K * 4 + i) * 2], z2), wv2, a0);\
        a1 = __builtin_elementwise_fma(                                       \
            __builtin_elementwise_max(eb + q2[(K * 4 + i) * 2 + 1], z2), wv2, a1);\
    }                                                                         \
} while (0)

#define ONLINE(J, X) do {                                                     \
    float mn = fmaxf(m_r[J], (X));                                            \
    s_r[J] = s_r[J] * __expf(m_r[J] - mn) + (ok ? __expf((X) - mn) : 0.f);    \
    m_r[J] = mn;                                                              \
} while (0)

#define COMPUTE(S) do {                                                       \
    const float* bufc = &seE[(S) & 1][0];                                     \
    _Pragma("unroll")                                                         \
    for (int rr = 0; rr < 4; ++rr) {                                          \
        const int lr = wv + 4 * rr;                                           \
        const float* er = bufc + lr * 300 + slot * 4;                         \
        f4 e0 = ld4(er);       f4 e1 = ld4(er + 64);  f4 e2 = ld4(er + 128);  \
        f4 e3 = ld4(er + 192); f4 e4 = ld4(er + 256);                         \
        v2f a0 = {0.f, 0.f}, a1 = {0.f, 0.f};                                 \
        v2f z2 = {0.f, 0.f};                                                  \
        MACK(e0, 0); MACK(e1, 1); MACK(e2, 2); MACK(e3, 3); MACK(e4, 4);      \
        float x0 = a0[0], x1 = a0[1], x2 = a1[0], x3 = a1[1];                 \
        _Pragma("unroll")                                                     \
        for (int sh = 1; sh <= 8; sh <<= 1) {                                 \
            x0 += __shfl_xor(x0, sh, 64); x1 += __shfl_xor(x1, sh, 64);       \
            x2 += __shfl_xor(x2, sh, 64); x3 += __shfl_xor(x3, sh, 64);       \
        }                                                                     \
        const int vr = v0 + (S) * 16 + lr;                                    \
        const bool ok = vr < V;                                               \
        x0 = ok ? x0 + bfull : NEG_HUGE;                                      \
        x1 = ok ? x1 + bfull : NEG_HUGE;                                      \
        x2 = ok ? x2 + bfull : NEG_HUGE;                                      \
        x3 = ok ? x3 + bfull : NEG_HUGE;                                      \
        ONLINE(0, x0); ONLINE(1, x1); ONLINE(2, x2); ONLINE(3, x3);           \
        if (slot == lr)                                                       \
            *(float4*)(satt + lr * 16 + bg * 4) = make_float4(x0, x1, x2, x3);\
    }                                                                         \
} while (0)

    STAGE(0);
    __syncthreads();   // buf0 + pads + (q/w loads waited by compiler)

    #pragma unroll
    for (int S = 0; S < 4; ++S) {
        if (S < 3) STAGE(S + 1);
        COMPUTE(S);
        __syncthreads();                     // satt complete
        {
            int b = t >> 4, r = t & 15;
            int vr2 = v0 + S * 16 + r;
            float val = satt[r * 16 + b];
            if (vr2 < V) att[(size_t)b * V + vr2] = val;
        }
        __syncthreads();                     // next buf staged; satt reads done
    }
#undef STAGE
#undef MACK
#undef ONLINE
#undef COMPUTE

    // block stats: all slots identical -> slot 0 lanes write per-wave (m,s)
    if (slot == 0) {
        *(float4*)(sms + wv * 16 + bg * 4)      = make_float4(m_r[0], m_r[1], m_r[2], m_r[3]);
        *(float4*)(sms + 64 + wv * 16 + bg * 4) = make_float4(s_r[0], s_r[1], s_r[2], s_r[3]);
    }
    __syncthreads();
    if (t < 16) {
        float m = NEG_HUGE, s = 0.f;
        #pragma unroll
        for (int w = 0; w < 4; ++w) {
            float mg = sms[w * 16 + t], sg = sms[64 + w * 16 + t];
            float mn = fmaxf(m, mg);
            s = s * __expf(m - mn) + sg * __expf(mg - mn);
            m = mn;
        }
        blkstats[((size_t)blockIdx.x * 16 + t) * 2]     = m;
        blkstats[((size_t)blockIdx.x * 16 + t) * 2 + 1] = s;
    }
}

// ---------------------------------------------------------------------------
// K3: combine per-block stats -> M_b, 1/S_b
__global__ void __launch_bounds__(64) k_combine(
    const float* __restrict__ blkstats, float* __restrict__ MS)
{
    int b = blockIdx.x, lane = threadIdx.x;
    float m = NEG_HUGE;
    for (int cc = lane; cc < NBLK; cc += 64)
        m = fmaxf(m, blkstats[(size_t)(cc * 16 + b) * 2]);
    #pragma unroll
    for (int off = 32; off; off >>= 1) m = fmaxf(m, __shfl_xor(m, off, 64));
    float s = 0.f;
    for (int cc = lane; cc < NBLK; cc += 64)
        s += blkstats[(size_t)(cc * 16 + b) * 2 + 1] *
             __expf(blkstats[(size_t)(cc * 16 + b) * 2] - m);
    #pragma unroll
    for (int off = 32; off; off >>= 1) s += __shfl_xor(s, off, 64);
    if (lane == 0) { MS[b * 2] = m; MS[b * 2 + 1] = 1.f / s; }
}

// ---------------------------------------------------------------------------
// K4 (fused alpha + wsum): per chunk c of RPC rows:
//   phase 1: alpha = exp(att-M)*invS in place AND staged in LDS
//   phase 2: thread t<300 owns column d=t, 16 batch partials (E coalesced).
__global__ void __launch_bounds__(320) k_awsum(
    const float* __restrict__ E, float* __restrict__ att,
    const float* __restrict__ MS, float* __restrict__ partials)
{
    __shared__ float sal[RPC * 16];   // [vv][b]
    int c = blockIdx.x, t = threadIdx.x;
    int v0 = c * RPC;
    int n = V - v0;
    if (n > RPC) n = RPC;
    if (n < 0) n = 0;

    for (int i = t; i < RPC * 16; i += 320) {
        int b = i / RPC, vv = i - b * RPC;
        float a = 0.f;
        if (vv < n) {
            float M = MS[b * 2], invS = MS[b * 2 + 1];
            size_t gi = (size_t)b * V + v0 + vv;
            a = __expf(att[gi] - M) * invS;
            att[gi] = a;
        }
        sal[vv * 16 + b] = a;
    }
    __syncthreads();

    if (t < D) {
        float acc[16];
        #pragma unroll
        for (int b = 0; b < 16; ++b) acc[b] = 0.f;
        #pragma unroll 8
        for (int vv = 0; vv < n; ++vv) {
            float e = E[(size_t)(v0 + vv) * D + t];
            const float* ap = sal + vv * 16;
            f4 a0 = ld4(ap), a1 = ld4(ap + 4), a2 = ld4(ap + 8), a3 = ld4(ap + 12);
            #pragma unroll
            for (int b = 0; b < 4; ++b) {
                acc[b]      = fmaf(a0.v[b], e, acc[b]);
                acc[b + 4]  = fmaf(a1.v[b], e, acc[b + 4]);
                acc[b + 8]  = fmaf(a2.v[b], e, acc[b + 8]);
                acc[b + 12] = fmaf(a3.v[b], e, acc[b + 12]);
            }
        }
        #pragma unroll
        for (int b = 0; b < 16; ++b)
            partials[(size_t)c * 4800 + b * D + t] = acc[b];
    }
}

// ---------------------------------------------------------------------------
// K5/K6: two-stage reduction of partials over NC chunks, float4-wide.
__global__ void __launch_bounds__(256) k_red1(
    const float* __restrict__ partials, float* __restrict__ tmp)
{
    int o4 = blockIdx.x * 256 + threadIdx.x;   // quad index, 1200 total
    if (o4 >= 1200) return;
    int y = blockIdx.y;
    float4 s = {0.f, 0.f, 0.f, 0.f};
    for (int c = y * 28; c < y * 28 + 28; ++c) {
        float4 p = *(const float4*)(partials + (size_t)c * 4800 + o4 * 4);
        s.x += p.x; s.y += p.y; s.z += p.z; s.w += p.w;
    }
    *(float4*)(tmp + (size_t)y * 4800 + o4 * 4) = s;
}

__global__ void __launch_bounds__(256) k_red2(
    const float* __restrict__ tmp, float* __restrict__ out)
{
    int o4 = blockIdx.x * 256 + threadIdx.x;
    if (o4 >= 1200) return;
    float4 s = {0.f, 0.f, 0.f, 0.f};
    #pragma unroll
    for (int y = 0; y < 16; ++y) {
        float4 p = *(const float4*)(tmp + (size_t)y * 4800 + o4 * 4);
        s.x += p.x; s.y += p.y; s.z += p.z; s.w += p.w;
    }
    *(float4*)(out + o4 * 4) = s;
}

// ---------------------------------------------------------------------------
extern "C" void kernel_launch(void* const* d_in, const int* in_sizes, int n_in,
                              void* d_out, int out_size, void* d_ws, size_t ws_size,
                              hipStream_t stream) {
    const float* dh   = (const float*)d_in[0];
    const float* E    = (const float*)d_in[1];
    const float* Wdec = (const float*)d_in[2];
    const float* bdec = (const float*)d_in[3];
    const float* wf   = (const float*)d_in[4];
    const float* bf   = (const float*)d_in[5];
    float* out = (float*)d_out;          // enc [0,4800), alpha [4800, ...)
    float* ws  = (float*)d_ws;

    float* q_t   = ws + WS_QT;
    float* stats = ws + WS_STAT;
    float* MS    = ws + WS_MS;
    float* part  = ws + WS_PART;
    float* tmp   = ws + WS_TMP;
    float* att   = out + 4800;

    k_query<<<(320 * 16) / 4, 256, 0, stream>>>(dh, Wdec, bdec, q_t);
    k_att<<<NBLK, 256, 0, stream>>>(E, q_t, wf, bf, att, stats);
    k_combine<<<B, 64, 0, stream>>>(stats, MS);
    k_awsum<<<NC, 320, 0, stream>>>(E, att, MS, part);
    k_red1<<<dim3(5, 16), 256, 0, stream>>>(part, tmp);
    k_red2<<<5, 256, 0, stream>>>(tmp, out);
}